// Round 5
// baseline (7037.131 us; speedup 1.0000x reference)
//
#include <hip/hip_runtime.h>
#include <hip/hip_bf16.h>

// Problem constants
#define BB 64
#define TT 256
#define HH 256
#define LL 15
#define E300 300
#define KPAD 608              // 600 padded to multiple of 32 (19 k-steps of 32)
#define NG 2048               // 2 directions * 4H gates
#define MROWS 16384           // B*T

typedef float  floatx4 __attribute__((ext_vector_type(4)));
typedef float  floatx2 __attribute__((ext_vector_type(2)));
typedef __bf16 bf16x8  __attribute__((ext_vector_type(8)));

// ALL float tensor inputs are float32 (per reference; proven rounds 1-3).
// R4: k_lstm was per-CU L2-fetch-bound (weights re-streamed every step).
// R5 FAILED: wreg[64] spilled to scratch -> 10.3 GB HBM scratch traffic.
// R6 FAILED: __launch_bounds__(1024,4) sets only waves-per-eu MIN; no change.
// R7 FAILED-but-informative: waves_per_eu(4,4) reached codegen (SGPR 32->112)
// yet VGPR stayed 64 -> the wreg[64] ALLOCA is demoted to scratch BEFORE
// register allocation (PromoteAlloca size cap); budget was never the issue.
// R8 fix: eliminate the alloca entirely. Weights repacked so each thread's
// 64 dwords are CONTIGUOUS (Wpk8[d][q][j][kk]); k_lstm holds them in 16
// NAMED uint4 variables (pure SSA -> mem2reg, cannot be demoted). Keep
// waves_per_eu(4,4) for the 128-VGPR budget (~100 live).

// ---------------- prep kernels ----------------

// X[row][0..299]=bf16(emb[id]), [300..599]=bf16(soft_emb[sid]), [600..607]=0
__global__ void k_embed(const int* __restrict__ ids, const int* __restrict__ sids,
                        const float* __restrict__ emb,
                        const float* __restrict__ semb,
                        __hip_bfloat16* __restrict__ X) {
    int row = blockIdx.x;
    int id  = ids[row];
    int sid = sids[row];
    const float* e0 = emb  + (long)id  * E300;
    const float* e1 = semb + (long)sid * E300;
    __hip_bfloat16* xr = X + (long)row * KPAD;
    for (int c = threadIdx.x; c < KPAD; c += blockDim.x) {
        float v;
        if (c < 300)      v = e0[c];
        else if (c < 600) v = e1[c - 300];
        else              v = 0.f;
        xr[c] = __float2bfloat16(v);
    }
}

// Wcat[2048][608]: rows 0..1023 = Wih_f (i,f,g,o), 1024..2047 = Wih_b; k padded w/ 0
__global__ void k_wcat(const float* __restrict__ Wf,
                       const float* __restrict__ Wb,
                       __hip_bfloat16* __restrict__ Wcat) {
    int r = blockIdx.x;
    const float* src = (r < 1024) ? (Wf + (long)r * 600)
                                  : (Wb + (long)(r - 1024) * 600);
    __hip_bfloat16* dst = Wcat + (long)r * KPAD;
    for (int c = threadIdx.x; c < KPAD; c += blockDim.x)
        dst[c] = __float2bfloat16((c < 600) ? src[c] : 0.f);
}

// Wpk8[d][q][j][kk] (q=k>>6, kk=k&63): packed fp8 e4m3 x4 gates for (j, k=q*64+kk).
// byte g = fp8(16 * Whh_dir[g*256+j][k]).  Per-(d,q,j) the 64 kk-dwords are
// CONTIGUOUS so k_lstm loads them as 16 uint4s.
__global__ void k_wpk(const float* __restrict__ Wf,
                      const float* __restrict__ Wb,
                      unsigned int* __restrict__ Wpk8) {
    int d = blockIdx.x >> 8;
    int k = blockIdx.x & 255;
    int j = threadIdx.x;
    const float* W = d ? Wb : Wf;
    float w0 = W[((long)(0 * 256 + j)) * 256 + k] * 16.f;
    float w1 = W[((long)(1 * 256 + j)) * 256 + k] * 16.f;
    float w2 = W[((long)(2 * 256 + j)) * 256 + k] * 16.f;
    float w3 = W[((long)(3 * 256 + j)) * 256 + k] * 16.f;
    int r = 0;
    r = __builtin_amdgcn_cvt_pk_fp8_f32(w0, w1, r, false);  // bytes 0,1 = i,f
    r = __builtin_amdgcn_cvt_pk_fp8_f32(w2, w3, r, true);   // bytes 2,3 = g,o
    Wpk8[(((long)d * 4 + (k >> 6)) * 256 + j) * 64 + (k & 63)] = (unsigned int)r;
}

// bias[dir][j4] = bih + bhh (fp32)
__global__ void k_bias(const float* __restrict__ bfi, const float* __restrict__ bfh,
                       const float* __restrict__ bbi, const float* __restrict__ bbh,
                       float* __restrict__ bias) {
    int i = blockIdx.x * blockDim.x + threadIdx.x;
    if (i < 2048) {
        int d = i >> 10, j = i & 1023;
        const float* b1 = d ? bbi : bfi;
        const float* b2 = d ? bbh : bfh;
        bias[i] = b1[j] + b2[j];
    }
}

// ---------------- input GEMM:  G[16384][2048] = X[16384][608] * Wcat[2048][608]^T ----------------
__global__ __launch_bounds__(256) void k_gemm(const __hip_bfloat16* __restrict__ A,
                                              const __hip_bfloat16* __restrict__ Bw,
                                              __hip_bfloat16* __restrict__ C) {
    __shared__ __align__(16) unsigned short As[128 * 40];  // 128 x 32, row stride 40 (pad)
    __shared__ __align__(16) unsigned short Bs[128 * 40];
    int bm = blockIdx.x, bn = blockIdx.y;
    int row0 = bm * 128, col0 = bn * 128;
    int tid = threadIdx.x;
    int wave = tid >> 6, lane = tid & 63;
    int wm = (wave >> 1) * 64, wn = (wave & 1) * 64;
    int l15 = lane & 15, quad = lane >> 4;
    floatx4 acc[4][4];
    #pragma unroll
    for (int i = 0; i < 4; ++i)
        #pragma unroll
        for (int j = 0; j < 4; ++j) acc[i][j] = (floatx4){0.f, 0.f, 0.f, 0.f};

    int r1 = tid >> 2, p1 = tid & 3;  // staging: chunk row / 16B-part

    for (int kk = 0; kk < KPAD; kk += 32) {
        uint4 a0 = *(const uint4*)(A  + ((long)(row0 + r1))      * KPAD + kk + p1 * 8);
        uint4 a1 = *(const uint4*)(A  + ((long)(row0 + 64 + r1)) * KPAD + kk + p1 * 8);
        uint4 b0 = *(const uint4*)(Bw + ((long)(col0 + r1))      * KPAD + kk + p1 * 8);
        uint4 b1 = *(const uint4*)(Bw + ((long)(col0 + 64 + r1)) * KPAD + kk + p1 * 8);
        *(uint4*)&As[r1 * 40 + p1 * 8]        = a0;
        *(uint4*)&As[(64 + r1) * 40 + p1 * 8] = a1;
        *(uint4*)&Bs[r1 * 40 + p1 * 8]        = b0;
        *(uint4*)&Bs[(64 + r1) * 40 + p1 * 8] = b1;
        __syncthreads();
        bf16x8 af[4], bfr[4];
        #pragma unroll
        for (int tm = 0; tm < 4; ++tm)
            af[tm] = *(const bf16x8*)&As[(wm + tm * 16 + l15) * 40 + quad * 8];
        #pragma unroll
        for (int tn = 0; tn < 4; ++tn)
            bfr[tn] = *(const bf16x8*)&Bs[(wn + tn * 16 + l15) * 40 + quad * 8];
        #pragma unroll
        for (int tm = 0; tm < 4; ++tm)
            #pragma unroll
            for (int tn = 0; tn < 4; ++tn)
                acc[tm][tn] = __builtin_amdgcn_mfma_f32_16x16x32_bf16(af[tm], bfr[tn], acc[tm][tn], 0, 0, 0);
        __syncthreads();
    }
    // C/D layout: m = quad*4 + reg, n = lane&15
    #pragma unroll
    for (int tm = 0; tm < 4; ++tm)
        #pragma unroll
        for (int tn = 0; tn < 4; ++tn) {
            int m0 = row0 + wm + tm * 16 + quad * 4;
            int n  = col0 + wn + tn * 16 + l15;
            #pragma unroll
            for (int r = 0; r < 4; ++r)
                C[((long)(m0 + r)) * NG + n] = __float2bfloat16(acc[tm][tn][r]);
        }
}

// ---------------- LSTM recurrence ----------------
// One block per (batch, direction), 1024 threads = 16 waves.
// Thread (q = tid>>8, j = tid&255): partial over k in [q*64, q*64+64) of the
// 4 gate pre-activations for hidden column j; 4-way LDS reduction per step.
// R8: weights in 16 NAMED uint4 vars (no alloca -> cannot be scratch-demoted);
// loaded once from the contiguous Wpk8[d][q][j][*] slice before the t-loop.
#define MAC1(w, hk) {                                                   \
    floatx2 wif = __builtin_amdgcn_cvt_pk_f32_fp8((w), false);          \
    floatx2 wgo = __builtin_amdgcn_cvt_pk_f32_fp8((w), true);           \
    floatx2 h2 = (floatx2){(hk), (hk)};                                 \
    aIF += h2 * wif;                                                    \
    aGO += h2 * wgo; }

#define MACW(W, base) {                                                 \
    floatx4 h4 = *(const floatx4*)&hq[(base)];                          \
    MAC1((W).x, h4[0]); MAC1((W).y, h4[1]);                             \
    MAC1((W).z, h4[2]); MAC1((W).w, h4[3]); }

__global__ __launch_bounds__(1024)
__attribute__((amdgpu_waves_per_eu(4, 4)))
void k_lstm(const __hip_bfloat16* __restrict__ G,    // [MROWS][NG]
            const unsigned int* __restrict__ Wpk8,   // [2][4][256][64] fp8x4
            const float* __restrict__ bias,          // [2][1024]
            const int* __restrict__ lengths,
            __hip_bfloat16* __restrict__ Hout) {     // [B][T][512]
    int dir = blockIdx.x & 1;
    int b   = blockIdx.x >> 1;
    int tid = threadIdx.x;
    int q   = tid >> 8;        // k-quarter
    int j   = tid & 255;       // gate-unit column
    __shared__ __align__(16) float hs[HH];          // holds h/16
    __shared__ __align__(16) float red[4][HH][4];   // [q][j][gate] = 16 KB
    float c = 0.f;
    float bi = 0.f, bf_ = 0.f, bg = 0.f, bo = 0.f;
    if (tid < HH) {
        const float* bs = bias + dir * 1024;
        bi = bs[j]; bf_ = bs[256 + j]; bg = bs[512 + j]; bo = bs[768 + j];
        hs[j] = 0.f;
    }
    int len = lengths[b];
    const float* hq = hs + q * 64;
    // time-invariant per-thread weight slice: 64 contiguous dwords = 16 uint4,
    // held in NAMED registers (no array, no alloca).
    const uint4* wt = (const uint4*)Wpk8 + (((long)dir * 4 + q) * 256 + j) * 16;
    uint4 W00 = wt[0],  W01 = wt[1],  W02 = wt[2],  W03 = wt[3];
    uint4 W04 = wt[4],  W05 = wt[5],  W06 = wt[6],  W07 = wt[7];
    uint4 W08 = wt[8],  W09 = wt[9],  W10 = wt[10], W11 = wt[11];
    uint4 W12 = wt[12], W13 = wt[13], W14 = wt[14], W15 = wt[15];
    __syncthreads();
    for (int t = 0; t < TT; ++t) {
        int tt = t;
        if (dir) tt = (t < len) ? (len - 1 - t) : t;
        const __hip_bfloat16* g = G + ((long)(b * TT + tt)) * NG + dir * 1024;
        float gi0 = 0.f, gi1 = 0.f, gi2 = 0.f, gi3 = 0.f;
        if (tid < HH) {   // prefetch gate inputs; consumed after the matvec
            gi0 = __bfloat162float(g[j]);
            gi1 = __bfloat162float(g[256 + j]);
            gi2 = __bfloat162float(g[512 + j]);
            gi3 = __bfloat162float(g[768 + j]);
        }
        floatx2 aIF = (floatx2){0.f, 0.f};
        floatx2 aGO = (floatx2){0.f, 0.f};
        MACW(W00,  0) MACW(W01,  4) MACW(W02,  8) MACW(W03, 12)
        MACW(W04, 16) MACW(W05, 20) MACW(W06, 24) MACW(W07, 28)
        MACW(W08, 32) MACW(W09, 36) MACW(W10, 40) MACW(W11, 44)
        MACW(W12, 48) MACW(W13, 52) MACW(W14, 56) MACW(W15, 60)
        *(floatx4*)&red[q][j][0] = (floatx4){aIF[0], aIF[1], aGO[0], aGO[1]};
        __syncthreads();
        if (tid < HH) {
            floatx4 r0 = *(const floatx4*)&red[0][j][0];
            floatx4 r1 = *(const floatx4*)&red[1][j][0];
            floatx4 r2 = *(const floatx4*)&red[2][j][0];
            floatx4 r3 = *(const floatx4*)&red[3][j][0];
            float ai = bi  + gi0 + r0[0] + r1[0] + r2[0] + r3[0];
            float af = bf_ + gi1 + r0[1] + r1[1] + r2[1] + r3[1];
            float ag = bg  + gi2 + r0[2] + r1[2] + r2[2] + r3[2];
            float ao = bo  + gi3 + r0[3] + r1[3] + r2[3] + r3[3];
            float ii = 1.f / (1.f + __expf(-ai));
            float ff = 1.f / (1.f + __expf(-af));
            float gg = tanhf(ag);
            float oo = 1.f / (1.f + __expf(-ao));
            c = ff * c + ii * gg;
            float h = oo * tanhf(c);
            hs[j] = h * 0.0625f;               // store h/16 for next step's matvec
            Hout[((long)(b * TT + tt)) * 512 + dir * HH + j] = __float2bfloat16(h);
        }
        __syncthreads();
    }
}

// ---------------- emissions: E[row][l] = h[row][0..511] . Wlin[l][0..511] + blin[l] ----------------
__global__ void k_emis(const __hip_bfloat16* __restrict__ Hc,   // [MROWS][512]
                       const float* __restrict__ Wlin,          // [15][512] fp32
                       const float* __restrict__ blin,
                       float* __restrict__ E) {
    int gid = blockIdx.x * blockDim.x + threadIdx.x;
    if (gid >= MROWS * LL) return;
    int row = gid / LL;
    int l = gid - row * LL;
    const __hip_bfloat16* hr = Hc + (long)row * 512;
    const float* wr = Wlin + l * 512;
    float s = blin[l];
    #pragma unroll 8
    for (int k = 0; k < 512; ++k)
        s = fmaf(__bfloat162float(hr[k]), wr[k], s);
    E[gid] = s;
}

// ---------------- CRF NLL per batch: one wave per batch ----------------
__global__ void k_crf(const float* __restrict__ E,      // [B][T][15]
                      const int* __restrict__ tags,     // [B][T]
                      const int* __restrict__ lengths,
                      const float* __restrict__ start_t,
                      const float* __restrict__ end_t,
                      const float* __restrict__ trans,  // [15][15] fp32
                      float* __restrict__ outp) {
    int b = blockIdx.x;
    int lane = threadIdx.x;
    int len = lengths[b];
    const float* Eb = E + (long)b * TT * LL;
    const int* tg = tags + b * TT;
    float tcol[LL];
    #pragma unroll
    for (int k = 0; k < LL; ++k)
        tcol[k] = (lane < LL) ? trans[k * LL + lane] : 0.f;
    float alpha = (lane < LL) ? start_t[lane] + Eb[lane] : -1e30f;
    for (int t = 1; t < len; ++t) {
        float e = (lane < LL) ? Eb[t * LL + lane] : 0.f;
        float m = -1e30f;
        float v[LL];
        #pragma unroll
        for (int k = 0; k < LL; ++k) {
            float ak = __shfl(alpha, k, 64);
            v[k] = ak + tcol[k];
            m = fmaxf(m, v[k]);
        }
        float s = 0.f;
        #pragma unroll
        for (int k = 0; k < LL; ++k) s += __expf(v[k] - m);
        alpha = m + __logf(s) + e;
    }
    // denominator
    float z = alpha + ((lane < LL) ? end_t[lane] : -1e30f);
    float m2 = -1e30f;
    #pragma unroll
    for (int k = 0; k < LL; ++k) m2 = fmaxf(m2, __shfl(z, k, 64));
    float s2 = 0.f;
    #pragma unroll
    for (int k = 0; k < LL; ++k) s2 += __expf(__shfl(z, k, 64) - m2);
    float den = m2 + __logf(s2);
    // numerator (lane-parallel over t, then wave-reduce)
    float part = 0.f;
    for (int t = lane; t < TT; t += 64) {
        if (t < len) {
            int tag = tg[t];
            part += Eb[t * LL + tag];
            if (t >= 1) part += trans[tg[t - 1] * LL + tag];
        }
    }
    #pragma unroll
    for (int off = 32; off > 0; off >>= 1) part += __shfl_down(part, off, 64);
    if (lane == 0) {
        float num = part + start_t[tg[0]] + end_t[tg[len - 1]];
        outp[b] = num - den;
    }
}

// output is float32 (reference output dtype)
__global__ void k_final(const float* __restrict__ outp, float* __restrict__ out) {
    int lane = threadIdx.x;
    float v = outp[lane];
    #pragma unroll
    for (int off = 32; off > 0; off >>= 1) v += __shfl_down(v, off, 64);
    if (lane == 0) out[0] = -v;   // loss = -sum(num - den)
}

// ---------------- launch ----------------
extern "C" void kernel_launch(void* const* d_in, const int* in_sizes, int n_in,
                              void* d_out, int out_size, void* d_ws, size_t ws_size,
                              hipStream_t stream) {
    const int* input_ids    = (const int*)d_in[0];
    const int* lengths      = (const int*)d_in[1];
    const int* softword_ids = (const int*)d_in[2];
    const int* label_ids    = (const int*)d_in[3];
    const float* emb      = (const float*)d_in[4];
    const float* soft_emb = (const float*)d_in[5];
    const float* Wih_f = (const float*)d_in[6];
    const float* Whh_f = (const float*)d_in[7];
    const float* bih_f = (const float*)d_in[8];
    const float* bhh_f = (const float*)d_in[9];
    const float* Wih_b = (const float*)d_in[10];
    const float* Whh_b = (const float*)d_in[11];
    const float* bih_b = (const float*)d_in[12];
    const float* bhh_b = (const float*)d_in[13];
    const float* Wlin  = (const float*)d_in[14];
    const float* blin  = (const float*)d_in[15];
    const float* start_t = (const float*)d_in[16];
    const float* end_t   = (const float*)d_in[17];
    const float* trans   = (const float*)d_in[18];

    // workspace layout, small buffers first (all offsets 256B aligned)
    char* base = (char*)d_ws;
    float*          part = (float*)(base);                             // 64*4          =        256
    float*          bias = (float*)(base + 256);                       // 2*1024*4      =      8,192
    float*          E    = (float*)(base + 8448);                      // 16384*15*4    =    983,040
    unsigned int*   Wpk8 = (unsigned int*)(base + 991488);             // 2*4*256*64*4  =    524,288 (region reserves 1 MB)
    __hip_bfloat16* Wcat = (__hip_bfloat16*)(base + 2040064);          // 2048*608*2    =  2,490,368
    __hip_bfloat16* Hc   = (__hip_bfloat16*)(base + 4530432);          // 64*256*512*2  = 16,777,216
    __hip_bfloat16* X    = (__hip_bfloat16*)(base + 21307648);         // 16384*608*2   = 19,922,944
    __hip_bfloat16* G    = (__hip_bfloat16*)(base + 41230592);         // 16384*2048*2  = 67,108,864
                                                                       // end: 108,339,456

    k_embed<<<MROWS, 64, 0, stream>>>(input_ids, softword_ids, emb, soft_emb, X);
    k_wcat<<<NG, 64, 0, stream>>>(Wih_f, Wih_b, Wcat);
    k_wpk<<<512, 256, 0, stream>>>(Whh_f, Whh_b, Wpk8);
    k_bias<<<8, 256, 0, stream>>>(bih_f, bhh_f, bih_b, bhh_b, bias);
    k_gemm<<<dim3(MROWS / 128, NG / 128), 256, 0, stream>>>(X, Wcat, G);
    k_lstm<<<BB * 2, 1024, 0, stream>>>(G, Wpk8, bias, lengths, Hc);
    k_emis<<<(MROWS * LL) / 256, 256, 0, stream>>>(Hc, Wlin, blin, E);
    k_crf<<<BB, 64, 0, stream>>>(E, label_ids, lengths, start_t, end_t, trans, part);
    k_final<<<1, 64, 0, stream>>>(part, (float*)d_out);
}

// Round 6
// 3621.908 us; speedup vs baseline: 1.9429x; 1.9429x over previous
//
#include <hip/hip_runtime.h>
#include <hip/hip_bf16.h>

// Problem constants
#define BB 64
#define TT 256
#define HH 256
#define LL 15
#define E300 300
#define KPAD 608              // 600 padded to multiple of 32 (19 k-steps of 32)
#define NG 2048               // 2 directions * 4H gates
#define MROWS 16384           // B*T

typedef float  floatx4 __attribute__((ext_vector_type(4)));
typedef float  floatx2 __attribute__((ext_vector_type(2)));
typedef __bf16 bf16x8  __attribute__((ext_vector_type(8)));

// ALL float tensor inputs are float32 (per reference; proven rounds 1-3).
// R4: k_lstm was per-CU L2-fetch-bound (weights re-streamed every step).
// R5-R8 FAILED: every attempt to hold 64 weight dwords in VGPRs spilled to
// scratch (10.6 GB HBM). R7/R8 proved the VGPR budget is hard-capped at 64
// on this toolchain (waves_per_eu(4,4) reached codegen -- SGPR 32->112 --
// but VGPR stayed 64; even 16 named uint4 SSA values spilled).
// R9 pivot: fit 64. Hybrid residency: 32 weight dwords in 8 named uint4
// (32 VGPRs, total pressure ~60) + 32 dwords in LDS (1024 thr x 128 B =
// 128 KB; gfx950 allows 160 KB/WG). Zero per-step global traffic. LDS
// weight reads are lane-stride-8B ds_read_b64 (2-way alias = free) and
// volatile (insurance vs LICM re-hoist->spill). Biases moved to LDS (-4 VGPR).

// ---------------- prep kernels ----------------

// X[row][0..299]=bf16(emb[id]), [300..599]=bf16(soft_emb[sid]), [600..607]=0
__global__ void k_embed(const int* __restrict__ ids, const int* __restrict__ sids,
                        const float* __restrict__ emb,
                        const float* __restrict__ semb,
                        __hip_bfloat16* __restrict__ X) {
    int row = blockIdx.x;
    int id  = ids[row];
    int sid = sids[row];
    const float* e0 = emb  + (long)id  * E300;
    const float* e1 = semb + (long)sid * E300;
    __hip_bfloat16* xr = X + (long)row * KPAD;
    for (int c = threadIdx.x; c < KPAD; c += blockDim.x) {
        float v;
        if (c < 300)      v = e0[c];
        else if (c < 600) v = e1[c - 300];
        else              v = 0.f;
        xr[c] = __float2bfloat16(v);
    }
}

// Wcat[2048][608]: rows 0..1023 = Wih_f (i,f,g,o), 1024..2047 = Wih_b; k padded w/ 0
__global__ void k_wcat(const float* __restrict__ Wf,
                       const float* __restrict__ Wb,
                       __hip_bfloat16* __restrict__ Wcat) {
    int r = blockIdx.x;
    const float* src = (r < 1024) ? (Wf + (long)r * 600)
                                  : (Wb + (long)(r - 1024) * 600);
    __hip_bfloat16* dst = Wcat + (long)r * KPAD;
    for (int c = threadIdx.x; c < KPAD; c += blockDim.x)
        dst[c] = __float2bfloat16((c < 600) ? src[c] : 0.f);
}

// Wpk8[d][q][j][kk] (q=k>>6, kk=k&63): packed fp8 e4m3 x4 gates for (j, k=q*64+kk).
// byte g = fp8(16 * Whh_dir[g*256+j][k]).  Per-(d,q,j) the 64 kk-dwords are
// CONTIGUOUS: dwords 0..31 -> k_lstm registers, 32..63 -> k_lstm LDS.
__global__ void k_wpk(const float* __restrict__ Wf,
                      const float* __restrict__ Wb,
                      unsigned int* __restrict__ Wpk8) {
    int d = blockIdx.x >> 8;
    int k = blockIdx.x & 255;
    int j = threadIdx.x;
    const float* W = d ? Wb : Wf;
    float w0 = W[((long)(0 * 256 + j)) * 256 + k] * 16.f;
    float w1 = W[((long)(1 * 256 + j)) * 256 + k] * 16.f;
    float w2 = W[((long)(2 * 256 + j)) * 256 + k] * 16.f;
    float w3 = W[((long)(3 * 256 + j)) * 256 + k] * 16.f;
    int r = 0;
    r = __builtin_amdgcn_cvt_pk_fp8_f32(w0, w1, r, false);  // bytes 0,1 = i,f
    r = __builtin_amdgcn_cvt_pk_fp8_f32(w2, w3, r, true);   // bytes 2,3 = g,o
    Wpk8[(((long)d * 4 + (k >> 6)) * 256 + j) * 64 + (k & 63)] = (unsigned int)r;
}

// bias[dir][j4] = bih + bhh (fp32)
__global__ void k_bias(const float* __restrict__ bfi, const float* __restrict__ bfh,
                       const float* __restrict__ bbi, const float* __restrict__ bbh,
                       float* __restrict__ bias) {
    int i = blockIdx.x * blockDim.x + threadIdx.x;
    if (i < 2048) {
        int d = i >> 10, j = i & 1023;
        const float* b1 = d ? bbi : bfi;
        const float* b2 = d ? bbh : bfh;
        bias[i] = b1[j] + b2[j];
    }
}

// ---------------- input GEMM:  G[16384][2048] = X[16384][608] * Wcat[2048][608]^T ----------------
__global__ __launch_bounds__(256) void k_gemm(const __hip_bfloat16* __restrict__ A,
                                              const __hip_bfloat16* __restrict__ Bw,
                                              __hip_bfloat16* __restrict__ C) {
    __shared__ __align__(16) unsigned short As[128 * 40];  // 128 x 32, row stride 40 (pad)
    __shared__ __align__(16) unsigned short Bs[128 * 40];
    int bm = blockIdx.x, bn = blockIdx.y;
    int row0 = bm * 128, col0 = bn * 128;
    int tid = threadIdx.x;
    int wave = tid >> 6, lane = tid & 63;
    int wm = (wave >> 1) * 64, wn = (wave & 1) * 64;
    int l15 = lane & 15, quad = lane >> 4;
    floatx4 acc[4][4];
    #pragma unroll
    for (int i = 0; i < 4; ++i)
        #pragma unroll
        for (int j = 0; j < 4; ++j) acc[i][j] = (floatx4){0.f, 0.f, 0.f, 0.f};

    int r1 = tid >> 2, p1 = tid & 3;  // staging: chunk row / 16B-part

    for (int kk = 0; kk < KPAD; kk += 32) {
        uint4 a0 = *(const uint4*)(A  + ((long)(row0 + r1))      * KPAD + kk + p1 * 8);
        uint4 a1 = *(const uint4*)(A  + ((long)(row0 + 64 + r1)) * KPAD + kk + p1 * 8);
        uint4 b0 = *(const uint4*)(Bw + ((long)(col0 + r1))      * KPAD + kk + p1 * 8);
        uint4 b1 = *(const uint4*)(Bw + ((long)(col0 + 64 + r1)) * KPAD + kk + p1 * 8);
        *(uint4*)&As[r1 * 40 + p1 * 8]        = a0;
        *(uint4*)&As[(64 + r1) * 40 + p1 * 8] = a1;
        *(uint4*)&Bs[r1 * 40 + p1 * 8]        = b0;
        *(uint4*)&Bs[(64 + r1) * 40 + p1 * 8] = b1;
        __syncthreads();
        bf16x8 af[4], bfr[4];
        #pragma unroll
        for (int tm = 0; tm < 4; ++tm)
            af[tm] = *(const bf16x8*)&As[(wm + tm * 16 + l15) * 40 + quad * 8];
        #pragma unroll
        for (int tn = 0; tn < 4; ++tn)
            bfr[tn] = *(const bf16x8*)&Bs[(wn + tn * 16 + l15) * 40 + quad * 8];
        #pragma unroll
        for (int tm = 0; tm < 4; ++tm)
            #pragma unroll
            for (int tn = 0; tn < 4; ++tn)
                acc[tm][tn] = __builtin_amdgcn_mfma_f32_16x16x32_bf16(af[tm], bfr[tn], acc[tm][tn], 0, 0, 0);
        __syncthreads();
    }
    // C/D layout: m = quad*4 + reg, n = lane&15
    #pragma unroll
    for (int tm = 0; tm < 4; ++tm)
        #pragma unroll
        for (int tn = 0; tn < 4; ++tn) {
            int m0 = row0 + wm + tm * 16 + quad * 4;
            int n  = col0 + wn + tn * 16 + l15;
            #pragma unroll
            for (int r = 0; r < 4; ++r)
                C[((long)(m0 + r)) * NG + n] = __float2bfloat16(acc[tm][tn][r]);
        }
}

// ---------------- LSTM recurrence ----------------
// One block per (batch, direction), 1024 threads = 16 waves.
// Thread (q = tid>>8, j = tid&255): partial over k in [q*64, q*64+64) of the
// 4 gate pre-activations for hidden column j; 4-way LDS reduction per step.
// R9: weights kk 0..31 in 8 named uint4 regs; kk 32..63 in 128 KB LDS.
#define MAC1(w, hk) {                                                   \
    floatx2 wif = __builtin_amdgcn_cvt_pk_f32_fp8((w), false);          \
    floatx2 wgo = __builtin_amdgcn_cvt_pk_f32_fp8((w), true);           \
    floatx2 h2 = (floatx2){(hk), (hk)};                                 \
    aIF += h2 * wif;                                                    \
    aGO += h2 * wgo; }

#define MACW(W, base) {                                                 \
    floatx4 h4 = *(const floatx4*)&hq[(base)];                          \
    MAC1((W).x, h4[0]); MAC1((W).y, h4[1]);                             \
    MAC1((W).z, h4[2]); MAC1((W).w, h4[3]); }

// LDS half: group g covers k = 32+4g .. 35+4g (pairs kk2=2g, 2g+1)
#define MACL(g) {                                                       \
    floatx4 h4 = *(const floatx4*)&hq[32 + 4 * (g)];                    \
    unsigned long long wa = *(volatile const unsigned long long*)&Wl[(2 * (g)) * 256];     \
    unsigned long long wb = *(volatile const unsigned long long*)&Wl[(2 * (g) + 1) * 256]; \
    MAC1((unsigned)wa, h4[0]); MAC1((unsigned)(wa >> 32), h4[1]);       \
    MAC1((unsigned)wb, h4[2]); MAC1((unsigned)(wb >> 32), h4[3]); }

__global__ __launch_bounds__(1024)
void k_lstm(const __hip_bfloat16* __restrict__ G,    // [MROWS][NG]
            const unsigned int* __restrict__ Wpk8,   // [2][4][256][64] fp8x4
            const float* __restrict__ bias,          // [2][1024]
            const int* __restrict__ lengths,
            __hip_bfloat16* __restrict__ Hout) {     // [B][T][512]
    int dir = blockIdx.x & 1;
    int b   = blockIdx.x >> 1;
    int tid = threadIdx.x;
    int q   = tid >> 8;        // k-quarter
    int j   = tid & 255;       // gate-unit column
    __shared__ __align__(16) float hs[HH];                    // holds h/16
    __shared__ __align__(16) float red[4][HH][4];             // [q][j][gate] = 16 KB
    __shared__ __align__(16) float bls[4][HH];                // biases, 4 KB
    __shared__ __align__(16) unsigned long long Wlds[64 * 256];  // [q*16+kk2][j] = 128 KB
    float c = 0.f;
    if (tid < HH) {
        const float* bs = bias + dir * 1024;
        bls[0][j] = bs[j];
        bls[1][j] = bs[256 + j];
        bls[2][j] = bs[512 + j];
        bls[3][j] = bs[768 + j];
        hs[j] = 0.f;
    }
    int len = lengths[b];
    const float* hq = hs + q * 64;
    // per-thread weight slice: 64 contiguous dwords. First 32 -> named regs.
    const uint4* wt = (const uint4*)Wpk8 + (((long)dir * 4 + q) * 256 + j) * 16;
    uint4 W00 = wt[0], W01 = wt[1], W02 = wt[2], W03 = wt[3];
    uint4 W04 = wt[4], W05 = wt[5], W06 = wt[6], W07 = wt[7];
    // Last 32 dwords -> LDS as 16 b64 entries at [q*16+kk2][j]
    unsigned long long* Wl = Wlds + q * 16 * 256 + j;
    #pragma unroll
    for (int i = 0; i < 8; ++i) {
        uint4 v = wt[8 + i];
        Wl[(2 * i) * 256]     = (unsigned long long)v.x | ((unsigned long long)v.y << 32);
        Wl[(2 * i + 1) * 256] = (unsigned long long)v.z | ((unsigned long long)v.w << 32);
    }
    __syncthreads();
    for (int t = 0; t < TT; ++t) {
        int tt = t;
        if (dir) tt = (t < len) ? (len - 1 - t) : t;
        const __hip_bfloat16* g = G + ((long)(b * TT + tt)) * NG + dir * 1024;
        float gi0 = 0.f, gi1 = 0.f, gi2 = 0.f, gi3 = 0.f;
        if (tid < HH) {   // prefetch gate inputs; consumed after the matvec
            gi0 = __bfloat162float(g[j]);
            gi1 = __bfloat162float(g[256 + j]);
            gi2 = __bfloat162float(g[512 + j]);
            gi3 = __bfloat162float(g[768 + j]);
        }
        floatx2 aIF = (floatx2){0.f, 0.f};
        floatx2 aGO = (floatx2){0.f, 0.f};
        // k order identical to previous rounds: kk 0..31 (regs), 32..63 (LDS)
        MACW(W00,  0) MACW(W01,  4) MACW(W02,  8) MACW(W03, 12)
        MACW(W04, 16) MACW(W05, 20) MACW(W06, 24) MACW(W07, 28)
        MACL(0) MACL(1) MACL(2) MACL(3)
        MACL(4) MACL(5) MACL(6) MACL(7)
        *(floatx4*)&red[q][j][0] = (floatx4){aIF[0], aIF[1], aGO[0], aGO[1]};
        __syncthreads();
        if (tid < HH) {
            floatx4 r0 = *(const floatx4*)&red[0][j][0];
            floatx4 r1 = *(const floatx4*)&red[1][j][0];
            floatx4 r2 = *(const floatx4*)&red[2][j][0];
            floatx4 r3 = *(const floatx4*)&red[3][j][0];
            float ai = bls[0][j] + gi0 + r0[0] + r1[0] + r2[0] + r3[0];
            float af = bls[1][j] + gi1 + r0[1] + r1[1] + r2[1] + r3[1];
            float ag = bls[2][j] + gi2 + r0[2] + r1[2] + r2[2] + r3[2];
            float ao = bls[3][j] + gi3 + r0[3] + r1[3] + r2[3] + r3[3];
            float ii = 1.f / (1.f + __expf(-ai));
            float ff = 1.f / (1.f + __expf(-af));
            float gg = tanhf(ag);
            float oo = 1.f / (1.f + __expf(-ao));
            c = ff * c + ii * gg;
            float h = oo * tanhf(c);
            hs[j] = h * 0.0625f;               // store h/16 for next step's matvec
            Hout[((long)(b * TT + tt)) * 512 + dir * HH + j] = __float2bfloat16(h);
        }
        __syncthreads();
    }
}

// ---------------- emissions: E[row][l] = h[row][0..511] . Wlin[l][0..511] + blin[l] ----------------
__global__ void k_emis(const __hip_bfloat16* __restrict__ Hc,   // [MROWS][512]
                       const float* __restrict__ Wlin,          // [15][512] fp32
                       const float* __restrict__ blin,
                       float* __restrict__ E) {
    int gid = blockIdx.x * blockDim.x + threadIdx.x;
    if (gid >= MROWS * LL) return;
    int row = gid / LL;
    int l = gid - row * LL;
    const __hip_bfloat16* hr = Hc + (long)row * 512;
    const float* wr = Wlin + l * 512;
    float s = blin[l];
    #pragma unroll 8
    for (int k = 0; k < 512; ++k)
        s = fmaf(__bfloat162float(hr[k]), wr[k], s);
    E[gid] = s;
}

// ---------------- CRF NLL per batch: one wave per batch ----------------
__global__ void k_crf(const float* __restrict__ E,      // [B][T][15]
                      const int* __restrict__ tags,     // [B][T]
                      const int* __restrict__ lengths,
                      const float* __restrict__ start_t,
                      const float* __restrict__ end_t,
                      const float* __restrict__ trans,  // [15][15] fp32
                      float* __restrict__ outp) {
    int b = blockIdx.x;
    int lane = threadIdx.x;
    int len = lengths[b];
    const float* Eb = E + (long)b * TT * LL;
    const int* tg = tags + b * TT;
    float tcol[LL];
    #pragma unroll
    for (int k = 0; k < LL; ++k)
        tcol[k] = (lane < LL) ? trans[k * LL + lane] : 0.f;
    float alpha = (lane < LL) ? start_t[lane] + Eb[lane] : -1e30f;
    for (int t = 1; t < len; ++t) {
        float e = (lane < LL) ? Eb[t * LL + lane] : 0.f;
        float m = -1e30f;
        float v[LL];
        #pragma unroll
        for (int k = 0; k < LL; ++k) {
            float ak = __shfl(alpha, k, 64);
            v[k] = ak + tcol[k];
            m = fmaxf(m, v[k]);
        }
        float s = 0.f;
        #pragma unroll
        for (int k = 0; k < LL; ++k) s += __expf(v[k] - m);
        alpha = m + __logf(s) + e;
    }
    // denominator
    float z = alpha + ((lane < LL) ? end_t[lane] : -1e30f);
    float m2 = -1e30f;
    #pragma unroll
    for (int k = 0; k < LL; ++k) m2 = fmaxf(m2, __shfl(z, k, 64));
    float s2 = 0.f;
    #pragma unroll
    for (int k = 0; k < LL; ++k) s2 += __expf(__shfl(z, k, 64) - m2);
    float den = m2 + __logf(s2);
    // numerator (lane-parallel over t, then wave-reduce)
    float part = 0.f;
    for (int t = lane; t < TT; t += 64) {
        if (t < len) {
            int tag = tg[t];
            part += Eb[t * LL + tag];
            if (t >= 1) part += trans[tg[t - 1] * LL + tag];
        }
    }
    #pragma unroll
    for (int off = 32; off > 0; off >>= 1) part += __shfl_down(part, off, 64);
    if (lane == 0) {
        float num = part + start_t[tg[0]] + end_t[tg[len - 1]];
        outp[b] = num - den;
    }
}

// output is float32 (reference output dtype)
__global__ void k_final(const float* __restrict__ outp, float* __restrict__ out) {
    int lane = threadIdx.x;
    float v = outp[lane];
    #pragma unroll
    for (int off = 32; off > 0; off >>= 1) v += __shfl_down(v, off, 64);
    if (lane == 0) out[0] = -v;   // loss = -sum(num - den)
}

// ---------------- launch ----------------
extern "C" void kernel_launch(void* const* d_in, const int* in_sizes, int n_in,
                              void* d_out, int out_size, void* d_ws, size_t ws_size,
                              hipStream_t stream) {
    const int* input_ids    = (const int*)d_in[0];
    const int* lengths      = (const int*)d_in[1];
    const int* softword_ids = (const int*)d_in[2];
    const int* label_ids    = (const int*)d_in[3];
    const float* emb      = (const float*)d_in[4];
    const float* soft_emb = (const float*)d_in[5];
    const float* Wih_f = (const float*)d_in[6];
    const float* Whh_f = (const float*)d_in[7];
    const float* bih_f = (const float*)d_in[8];
    const float* bhh_f = (const float*)d_in[9];
    const float* Wih_b = (const float*)d_in[10];
    const float* Whh_b = (const float*)d_in[11];
    const float* bih_b = (const float*)d_in[12];
    const float* bhh_b = (const float*)d_in[13];
    const float* Wlin  = (const float*)d_in[14];
    const float* blin  = (const float*)d_in[15];
    const float* start_t = (const float*)d_in[16];
    const float* end_t   = (const float*)d_in[17];
    const float* trans   = (const float*)d_in[18];

    // workspace layout, small buffers first (all offsets 256B aligned)
    char* base = (char*)d_ws;
    float*          part = (float*)(base);                             // 64*4          =        256
    float*          bias = (float*)(base + 256);                       // 2*1024*4      =      8,192
    float*          E    = (float*)(base + 8448);                      // 16384*15*4    =    983,040
    unsigned int*   Wpk8 = (unsigned int*)(base + 991488);             // 2*4*256*64*4  =    524,288 (region reserves 1 MB)
    __hip_bfloat16* Wcat = (__hip_bfloat16*)(base + 2040064);          // 2048*608*2    =  2,490,368
    __hip_bfloat16* Hc   = (__hip_bfloat16*)(base + 4530432);          // 64*256*512*2  = 16,777,216
    __hip_bfloat16* X    = (__hip_bfloat16*)(base + 21307648);         // 16384*608*2   = 19,922,944
    __hip_bfloat16* G    = (__hip_bfloat16*)(base + 41230592);         // 16384*2048*2  = 67,108,864
                                                                       // end: 108,339,456

    k_embed<<<MROWS, 64, 0, stream>>>(input_ids, softword_ids, emb, soft_emb, X);
    k_wcat<<<NG, 64, 0, stream>>>(Wih_f, Wih_b, Wcat);
    k_wpk<<<512, 256, 0, stream>>>(Whh_f, Whh_b, Wpk8);
    k_bias<<<8, 256, 0, stream>>>(bih_f, bhh_f, bih_b, bhh_b, bias);
    k_gemm<<<dim3(MROWS / 128, NG / 128), 256, 0, stream>>>(X, Wcat, G);
    k_lstm<<<BB * 2, 1024, 0, stream>>>(G, Wpk8, bias, lengths, Hc);
    k_emis<<<(MROWS * LL) / 256, 256, 0, stream>>>(Hc, Wlin, blin, E);
    k_crf<<<BB, 64, 0, stream>>>(E, label_ids, lengths, start_t, end_t, trans, part);
    k_final<<<1, 64, 0, stream>>>(part, (float*)d_out);
}

// Round 7
// 1520.425 us; speedup vs baseline: 4.6284x; 2.3822x over previous
//
#include <hip/hip_runtime.h>
#include <hip/hip_bf16.h>

// Problem constants
#define BB 64
#define TT 256
#define HH 256
#define LL 15
#define E300 300
#define KPAD 608              // 600 padded to multiple of 32 (19 k-steps of 32)
#define NG 2048               // 2 directions * 4H gates
#define MROWS 16384           // B*T

typedef float  floatx4 __attribute__((ext_vector_type(4)));
typedef float  floatx2 __attribute__((ext_vector_type(2)));
typedef __bf16 bf16x8  __attribute__((ext_vector_type(8)));

// ALL float tensor inputs are float32 (per reference; proven rounds 1-3).
// R4: k_lstm L2-fetch-bound (all 64 wdwords re-streamed/step) -> 1187us.
// R5-R8: every >64-VGPR design spilled to scratch; VGPR budget is HARD 64.
// R9: 32 reg + 32 LDS -> allocator kept only ~16 reg dwords, spilled ~16
//     (2.0 GB scratch, 3290us). Lesson: only ~16 weight dwords fit in regs.
// R10: three-tier fit: 16 dwords in regs (allocator-proven) + 32 in LDS
//      (128 KB, volatile) + 16 STREAMED from L2 each step (64 KB/block/step,
//      L2-resident, ~1.16us/step at R4's measured stream rate, overlapped
//      with VALU). Opaque-pointer asm stops LICM from hoisting stream loads
//      into permanently-live regs. G repacked gate-interleaved (free, via
//      Wcat row permutation) so gate inputs are one uint2 load (-2 regs,
//      -3 loads). Math and FP order identical to R9.

// ---------------- prep kernels ----------------

// X[row][0..299]=bf16(emb[id]), [300..599]=bf16(soft_emb[sid]), [600..607]=0
__global__ void k_embed(const int* __restrict__ ids, const int* __restrict__ sids,
                        const float* __restrict__ emb,
                        const float* __restrict__ semb,
                        __hip_bfloat16* __restrict__ X) {
    int row = blockIdx.x;
    int id  = ids[row];
    int sid = sids[row];
    const float* e0 = emb  + (long)id  * E300;
    const float* e1 = semb + (long)sid * E300;
    __hip_bfloat16* xr = X + (long)row * KPAD;
    for (int c = threadIdx.x; c < KPAD; c += blockDim.x) {
        float v;
        if (c < 300)      v = e0[c];
        else if (c < 600) v = e1[c - 300];
        else              v = 0.f;
        xr[c] = __float2bfloat16(v);
    }
}

// Wcat[2048][608] GATE-INTERLEAVED: row r -> dir=r>>10, j=(r&1023)>>2, gate=r&3,
// source row = gate*256+j of Wih_dir. G then comes out as [row][dir][j][gate].
__global__ void k_wcat(const float* __restrict__ Wf,
                       const float* __restrict__ Wb,
                       __hip_bfloat16* __restrict__ Wcat) {
    int r = blockIdx.x;
    int dir = r >> 10, rr = r & 1023, j = rr >> 2, gate = rr & 3;
    const float* src = (dir ? Wb : Wf) + (long)(gate * 256 + j) * 600;
    __hip_bfloat16* dst = Wcat + (long)r * KPAD;
    for (int c = threadIdx.x; c < KPAD; c += blockDim.x)
        dst[c] = __float2bfloat16((c < 600) ? src[c] : 0.f);
}

// Wpk8[d][q][j][kk] (q=k>>6, kk=k&63): packed fp8 e4m3 x4 gates for (j, k=q*64+kk).
// byte g = fp8(16 * Whh_dir[g*256+j][k]).  Per-(d,q,j) the 64 kk-dwords are
// CONTIGUOUS: dwords 0..15 -> regs, 16..47 -> LDS, 48..63 -> per-step L2 stream.
__global__ void k_wpk(const float* __restrict__ Wf,
                      const float* __restrict__ Wb,
                      unsigned int* __restrict__ Wpk8) {
    int d = blockIdx.x >> 8;
    int k = blockIdx.x & 255;
    int j = threadIdx.x;
    const float* W = d ? Wb : Wf;
    float w0 = W[((long)(0 * 256 + j)) * 256 + k] * 16.f;
    float w1 = W[((long)(1 * 256 + j)) * 256 + k] * 16.f;
    float w2 = W[((long)(2 * 256 + j)) * 256 + k] * 16.f;
    float w3 = W[((long)(3 * 256 + j)) * 256 + k] * 16.f;
    int r = 0;
    r = __builtin_amdgcn_cvt_pk_fp8_f32(w0, w1, r, false);  // bytes 0,1 = i,f
    r = __builtin_amdgcn_cvt_pk_fp8_f32(w2, w3, r, true);   // bytes 2,3 = g,o
    Wpk8[(((long)d * 4 + (k >> 6)) * 256 + j) * 64 + (k & 63)] = (unsigned int)r;
}

// bias[dir][j4] = bih + bhh (fp32)
__global__ void k_bias(const float* __restrict__ bfi, const float* __restrict__ bfh,
                       const float* __restrict__ bbi, const float* __restrict__ bbh,
                       float* __restrict__ bias) {
    int i = blockIdx.x * blockDim.x + threadIdx.x;
    if (i < 2048) {
        int d = i >> 10, j = i & 1023;
        const float* b1 = d ? bbi : bfi;
        const float* b2 = d ? bbh : bfh;
        bias[i] = b1[j] + b2[j];
    }
}

// ---------------- input GEMM:  G[16384][2048] = X[16384][608] * Wcat[2048][608]^T ----------------
__global__ __launch_bounds__(256) void k_gemm(const __hip_bfloat16* __restrict__ A,
                                              const __hip_bfloat16* __restrict__ Bw,
                                              __hip_bfloat16* __restrict__ C) {
    __shared__ __align__(16) unsigned short As[128 * 40];  // 128 x 32, row stride 40 (pad)
    __shared__ __align__(16) unsigned short Bs[128 * 40];
    int bm = blockIdx.x, bn = blockIdx.y;
    int row0 = bm * 128, col0 = bn * 128;
    int tid = threadIdx.x;
    int wave = tid >> 6, lane = tid & 63;
    int wm = (wave >> 1) * 64, wn = (wave & 1) * 64;
    int l15 = lane & 15, quad = lane >> 4;
    floatx4 acc[4][4];
    #pragma unroll
    for (int i = 0; i < 4; ++i)
        #pragma unroll
        for (int j = 0; j < 4; ++j) acc[i][j] = (floatx4){0.f, 0.f, 0.f, 0.f};

    int r1 = tid >> 2, p1 = tid & 3;  // staging: chunk row / 16B-part

    for (int kk = 0; kk < KPAD; kk += 32) {
        uint4 a0 = *(const uint4*)(A  + ((long)(row0 + r1))      * KPAD + kk + p1 * 8);
        uint4 a1 = *(const uint4*)(A  + ((long)(row0 + 64 + r1)) * KPAD + kk + p1 * 8);
        uint4 b0 = *(const uint4*)(Bw + ((long)(col0 + r1))      * KPAD + kk + p1 * 8);
        uint4 b1 = *(const uint4*)(Bw + ((long)(col0 + 64 + r1)) * KPAD + kk + p1 * 8);
        *(uint4*)&As[r1 * 40 + p1 * 8]        = a0;
        *(uint4*)&As[(64 + r1) * 40 + p1 * 8] = a1;
        *(uint4*)&Bs[r1 * 40 + p1 * 8]        = b0;
        *(uint4*)&Bs[(64 + r1) * 40 + p1 * 8] = b1;
        __syncthreads();
        bf16x8 af[4], bfr[4];
        #pragma unroll
        for (int tm = 0; tm < 4; ++tm)
            af[tm] = *(const bf16x8*)&As[(wm + tm * 16 + l15) * 40 + quad * 8];
        #pragma unroll
        for (int tn = 0; tn < 4; ++tn)
            bfr[tn] = *(const bf16x8*)&Bs[(wn + tn * 16 + l15) * 40 + quad * 8];
        #pragma unroll
        for (int tm = 0; tm < 4; ++tm)
            #pragma unroll
            for (int tn = 0; tn < 4; ++tn)
                acc[tm][tn] = __builtin_amdgcn_mfma_f32_16x16x32_bf16(af[tm], bfr[tn], acc[tm][tn], 0, 0, 0);
        __syncthreads();
    }
    // C/D layout: m = quad*4 + reg, n = lane&15
    #pragma unroll
    for (int tm = 0; tm < 4; ++tm)
        #pragma unroll
        for (int tn = 0; tn < 4; ++tn) {
            int m0 = row0 + wm + tm * 16 + quad * 4;
            int n  = col0 + wn + tn * 16 + l15;
            #pragma unroll
            for (int r = 0; r < 4; ++r)
                C[((long)(m0 + r)) * NG + n] = __float2bfloat16(acc[tm][tn][r]);
        }
}

// ---------------- LSTM recurrence ----------------
// One block per (batch, direction), 1024 threads = 16 waves.
// Thread (q = tid>>8, j = tid&255): partial over k in [q*64, q*64+64) of the
// 4 gate pre-activations for hidden column j; 4-way LDS reduction per step.
// R10 residency: kk 0..15 regs / 16..47 LDS (volatile) / 48..63 L2 stream.
#define MAC1(w, hk) {                                                   \
    floatx2 wif = __builtin_amdgcn_cvt_pk_f32_fp8((w), false);          \
    floatx2 wgo = __builtin_amdgcn_cvt_pk_f32_fp8((w), true);           \
    floatx2 h2 = (floatx2){(hk), (hk)};                                 \
    aIF += h2 * wif;                                                    \
    aGO += h2 * wgo; }

#define MACW(W, base) {                                                 \
    floatx4 h4 = *(const floatx4*)&hq[(base)];                          \
    MAC1((W).x, h4[0]); MAC1((W).y, h4[1]);                             \
    MAC1((W).z, h4[2]); MAC1((W).w, h4[3]); }

// LDS half: group g covers k = 16+4g .. 19+4g
#define MACL(g) {                                                       \
    floatx4 h4 = *(const floatx4*)&hq[16 + 4 * (g)];                    \
    unsigned long long wa = *(volatile const unsigned long long*)&Wl[(2 * (g)) * 256];     \
    unsigned long long wb = *(volatile const unsigned long long*)&Wl[(2 * (g) + 1) * 256]; \
    MAC1((unsigned)wa, h4[0]); MAC1((unsigned)(wa >> 32), h4[1]);       \
    MAC1((unsigned)wb, h4[2]); MAC1((unsigned)(wb >> 32), h4[3]); }

__device__ __forceinline__ float b2f(unsigned u) {
    union { unsigned i; float f; } v; v.i = u << 16; return v.f;
}

__global__ __launch_bounds__(1024)
void k_lstm(const __hip_bfloat16* __restrict__ G,    // [MROWS][2][256][4] gate-interleaved
            const unsigned int* __restrict__ Wpk8,   // [2][4][256][64] fp8x4
            const float* __restrict__ bias,          // [2][1024]
            const int* __restrict__ lengths,
            __hip_bfloat16* __restrict__ Hout) {     // [B][T][512]
    int dir = blockIdx.x & 1;
    int b   = blockIdx.x >> 1;
    int tid = threadIdx.x;
    int q   = tid >> 8;        // k-quarter
    int j   = tid & 255;       // gate-unit column
    __shared__ __align__(16) float hs[HH];                    // holds h/16
    __shared__ __align__(16) float red[4][HH][4];             // [q][j][gate] = 16 KB
    __shared__ __align__(16) float bls[4][HH];                // biases, 4 KB
    __shared__ __align__(16) unsigned long long Wlds[64 * 256];  // [q*16+kk2][j] = 128 KB
    float c = 0.f;
    if (tid < HH) {
        const float* bs = bias + dir * 1024;
        bls[0][j] = bs[j];
        bls[1][j] = bs[256 + j];
        bls[2][j] = bs[512 + j];
        bls[3][j] = bs[768 + j];
        hs[j] = 0.f;
    }
    int len = lengths[b];
    const float* hq = hs + q * 64;
    // per-thread weight slice: 64 contiguous dwords at wt[0..15] (uint4 units)
    const uint4* wt = (const uint4*)Wpk8 + (((long)dir * 4 + q) * 256 + j) * 16;
    // tier 1: kk 0..15 in 4 named uint4 regs (R9 proved ~16 dwords stay resident)
    uint4 W00 = wt[0], W01 = wt[1], W02 = wt[2], W03 = wt[3];
    // tier 2: kk 16..47 -> LDS as 16 b64 entries at [q*16+kk2][j]
    unsigned long long* Wl = Wlds + q * 16 * 256 + j;
    #pragma unroll
    for (int i = 0; i < 8; ++i) {
        uint4 v = wt[4 + i];
        Wl[(2 * i) * 256]     = (unsigned long long)v.x | ((unsigned long long)v.y << 32);
        Wl[(2 * i + 1) * 256] = (unsigned long long)v.z | ((unsigned long long)v.w << 32);
    }
    // tier 3: kk 48..63 streamed from L2 every step (address kept opaque below)
    unsigned long wsa = (unsigned long)(wt + 12);
    const __hip_bfloat16* Gb = G + ((long)b * TT) * NG + dir * 1024;
    __syncthreads();
    for (int t = 0; t < TT; ++t) {
        int tt = t;
        if (dir) tt = (t < len) ? (len - 1 - t) : t;
        // issue stream loads first (L2-resident; hidden under reg/LDS MACs).
        // opaque asm: compiler can't prove address invariant -> no LICM hoist.
        unsigned long wsv = wsa;
        asm volatile("" : "+v"(wsv));
        const uint4* ws = (const uint4*)wsv;
        uint4 S0 = ws[0], S1 = ws[1], S2 = ws[2], S3 = ws[3];
        uint2 gp = (uint2){0u, 0u};
        if (tid < HH)   // packed gate inputs (i,f,g,o for unit j): one 8B load
            gp = *(const uint2*)(Gb + (long)tt * NG + j * 4);
        floatx2 aIF = (floatx2){0.f, 0.f};
        floatx2 aGO = (floatx2){0.f, 0.f};
        // k ascending 0..63, same FP order as R9
        MACW(W00, 0) MACW(W01, 4) MACW(W02, 8) MACW(W03, 12)
        MACL(0) MACL(1) MACL(2) MACL(3)
        MACL(4) MACL(5) MACL(6) MACL(7)
        MACW(S0, 48) MACW(S1, 52) MACW(S2, 56) MACW(S3, 60)
        *(floatx4*)&red[q][j][0] = (floatx4){aIF[0], aIF[1], aGO[0], aGO[1]};
        __syncthreads();
        if (tid < HH) {
            floatx4 r0 = *(const floatx4*)&red[0][j][0];
            floatx4 r1 = *(const floatx4*)&red[1][j][0];
            floatx4 r2 = *(const floatx4*)&red[2][j][0];
            floatx4 r3 = *(const floatx4*)&red[3][j][0];
            float ai = bls[0][j] + b2f(gp.x & 0xffffu)  + r0[0] + r1[0] + r2[0] + r3[0];
            float af = bls[1][j] + b2f(gp.x >> 16)      + r0[1] + r1[1] + r2[1] + r3[1];
            float ag = bls[2][j] + b2f(gp.y & 0xffffu)  + r0[2] + r1[2] + r2[2] + r3[2];
            float ao = bls[3][j] + b2f(gp.y >> 16)      + r0[3] + r1[3] + r2[3] + r3[3];
            float ii = 1.f / (1.f + __expf(-ai));
            float ff = 1.f / (1.f + __expf(-af));
            float gg = tanhf(ag);
            float oo = 1.f / (1.f + __expf(-ao));
            c = ff * c + ii * gg;
            float h = oo * tanhf(c);
            hs[j] = h * 0.0625f;               // store h/16 for next step's matvec
            Hout[((long)(b * TT + tt)) * 512 + dir * HH + j] = __float2bfloat16(h);
        }
        __syncthreads();
    }
}

// ---------------- emissions: E[row][l] = h[row][0..511] . Wlin[l][0..511] + blin[l] ----------------
__global__ void k_emis(const __hip_bfloat16* __restrict__ Hc,   // [MROWS][512]
                       const float* __restrict__ Wlin,          // [15][512] fp32
                       const float* __restrict__ blin,
                       float* __restrict__ E) {
    int gid = blockIdx.x * blockDim.x + threadIdx.x;
    if (gid >= MROWS * LL) return;
    int row = gid / LL;
    int l = gid - row * LL;
    const __hip_bfloat16* hr = Hc + (long)row * 512;
    const float* wr = Wlin + l * 512;
    float s = blin[l];
    #pragma unroll 8
    for (int k = 0; k < 512; ++k)
        s = fmaf(__bfloat162float(hr[k]), wr[k], s);
    E[gid] = s;
}

// ---------------- CRF NLL per batch: one wave per batch ----------------
__global__ void k_crf(const float* __restrict__ E,      // [B][T][15]
                      const int* __restrict__ tags,     // [B][T]
                      const int* __restrict__ lengths,
                      const float* __restrict__ start_t,
                      const float* __restrict__ end_t,
                      const float* __restrict__ trans,  // [15][15] fp32
                      float* __restrict__ outp) {
    int b = blockIdx.x;
    int lane = threadIdx.x;
    int len = lengths[b];
    const float* Eb = E + (long)b * TT * LL;
    const int* tg = tags + b * TT;
    float tcol[LL];
    #pragma unroll
    for (int k = 0; k < LL; ++k)
        tcol[k] = (lane < LL) ? trans[k * LL + lane] : 0.f;
    float alpha = (lane < LL) ? start_t[lane] + Eb[lane] : -1e30f;
    for (int t = 1; t < len; ++t) {
        float e = (lane < LL) ? Eb[t * LL + lane] : 0.f;
        float m = -1e30f;
        float v[LL];
        #pragma unroll
        for (int k = 0; k < LL; ++k) {
            float ak = __shfl(alpha, k, 64);
            v[k] = ak + tcol[k];
            m = fmaxf(m, v[k]);
        }
        float s = 0.f;
        #pragma unroll
        for (int k = 0; k < LL; ++k) s += __expf(v[k] - m);
        alpha = m + __logf(s) + e;
    }
    // denominator
    float z = alpha + ((lane < LL) ? end_t[lane] : -1e30f);
    float m2 = -1e30f;
    #pragma unroll
    for (int k = 0; k < LL; ++k) m2 = fmaxf(m2, __shfl(z, k, 64));
    float s2 = 0.f;
    #pragma unroll
    for (int k = 0; k < LL; ++k) s2 += __expf(__shfl(z, k, 64) - m2);
    float den = m2 + __logf(s2);
    // numerator (lane-parallel over t, then wave-reduce)
    float part = 0.f;
    for (int t = lane; t < TT; t += 64) {
        if (t < len) {
            int tag = tg[t];
            part += Eb[t * LL + tag];
            if (t >= 1) part += trans[tg[t - 1] * LL + tag];
        }
    }
    #pragma unroll
    for (int off = 32; off > 0; off >>= 1) part += __shfl_down(part, off, 64);
    if (lane == 0) {
        float num = part + start_t[tg[0]] + end_t[tg[len - 1]];
        outp[b] = num - den;
    }
}

// output is float32 (reference output dtype)
__global__ void k_final(const float* __restrict__ outp, float* __restrict__ out) {
    int lane = threadIdx.x;
    float v = outp[lane];
    #pragma unroll
    for (int off = 32; off > 0; off >>= 1) v += __shfl_down(v, off, 64);
    if (lane == 0) out[0] = -v;   // loss = -sum(num - den)
}

// ---------------- launch ----------------
extern "C" void kernel_launch(void* const* d_in, const int* in_sizes, int n_in,
                              void* d_out, int out_size, void* d_ws, size_t ws_size,
                              hipStream_t stream) {
    const int* input_ids    = (const int*)d_in[0];
    const int* lengths      = (const int*)d_in[1];
    const int* softword_ids = (const int*)d_in[2];
    const int* label_ids    = (const int*)d_in[3];
    const float* emb      = (const float*)d_in[4];
    const float* soft_emb = (const float*)d_in[5];
    const float* Wih_f = (const float*)d_in[6];
    const float* Whh_f = (const float*)d_in[7];
    const float* bih_f = (const float*)d_in[8];
    const float* bhh_f = (const float*)d_in[9];
    const float* Wih_b = (const float*)d_in[10];
    const float* Whh_b = (const float*)d_in[11];
    const float* bih_b = (const float*)d_in[12];
    const float* bhh_b = (const float*)d_in[13];
    const float* Wlin  = (const float*)d_in[14];
    const float* blin  = (const float*)d_in[15];
    const float* start_t = (const float*)d_in[16];
    const float* end_t   = (const float*)d_in[17];
    const float* trans   = (const float*)d_in[18];

    // workspace layout, small buffers first (all offsets 256B aligned)
    char* base = (char*)d_ws;
    float*          part = (float*)(base);                             // 64*4          =        256
    float*          bias = (float*)(base + 256);                       // 2*1024*4      =      8,192
    float*          E    = (float*)(base + 8448);                      // 16384*15*4    =    983,040
    unsigned int*   Wpk8 = (unsigned int*)(base + 991488);             // 2*4*256*64*4  =    524,288 (region reserves 1 MB)
    __hip_bfloat16* Wcat = (__hip_bfloat16*)(base + 2040064);          // 2048*608*2    =  2,490,368
    __hip_bfloat16* Hc   = (__hip_bfloat16*)(base + 4530432);          // 64*256*512*2  = 16,777,216
    __hip_bfloat16* X    = (__hip_bfloat16*)(base + 21307648);         // 16384*608*2   = 19,922,944
    __hip_bfloat16* G    = (__hip_bfloat16*)(base + 41230592);         // 16384*2048*2  = 67,108,864
                                                                       // end: 108,339,456

    k_embed<<<MROWS, 64, 0, stream>>>(input_ids, softword_ids, emb, soft_emb, X);
    k_wcat<<<NG, 64, 0, stream>>>(Wih_f, Wih_b, Wcat);
    k_wpk<<<512, 256, 0, stream>>>(Whh_f, Whh_b, Wpk8);
    k_bias<<<8, 256, 0, stream>>>(bih_f, bhh_f, bih_b, bhh_b, bias);
    k_gemm<<<dim3(MROWS / 128, NG / 128), 256, 0, stream>>>(X, Wcat, G);
    k_lstm<<<BB * 2, 1024, 0, stream>>>(G, Wpk8, bias, lengths, Hc);
    k_emis<<<(MROWS * LL) / 256, 256, 0, stream>>>(Hc, Wlin, blin, E);
    k_crf<<<BB, 64, 0, stream>>>(E, label_ids, lengths, start_t, end_t, trans, part);
    k_final<<<1, 64, 0, stream>>>(part, (float*)d_out);
}